// Round 7
// baseline (7995.360 us; speedup 1.0000x reference)
//
#include <hip/hip_runtime.h>

#define BATCH 8
#define KSPLIT 4                       // blocks (CUs) per batch
#define NBLK (BATCH * KSPLIT)          // 32 blocks, all co-resident
#define N 32768
#define NPOINT 2048
#define NT 512                         // threads per block (8 waves)
#define NW 8                           // waves per block
#define NSLOT (KSPLIT * NW)            // 32 published keys per iteration
#define QB (N / 2 / KSPLIT)            // f2 elems per block = 4096

typedef __attribute__((ext_vector_type(2))) float f2;

// Barrier-free multi-CU FPS.  Each batch split over KSPLIT blocks (swizzled
// onto one XCD: blk = k*8 + b).  All point state in registers (16 pts/thr).
// Per iteration each WAVE publishes a self-contained u64 key
//   (dist_bits << 32) | (N - idx)      (always nonzero: N-idx >= 1)
// to its own slot gslot[b][j][k*8+w] with a relaxed agent-scope store, then
// polls all 32 slots (one per lane, plain atomic loads - no RMWs), combines
// them with a shfl max-reduce, and proceeds.  Zero __syncthreads, zero LDS,
// zero fences: the data rides in the flag word, slots are per-iteration.
// Max dist + lowest original index on ties (dist >= 0 -> bits monotone).
// Bit-exact numpy semantics: contract off, (xx+yy)+zz order, no FMA.
// R5 bug fixed: output written by k==0 block of EACH batch (was blk==0).

#define REP8(M)  M(0) M(1) M(2) M(3) M(4) M(5) M(6) M(7)
#define REP8R(M) M(7) M(6) M(5) M(4) M(3) M(2) M(1) M(0)

__global__ __attribute__((amdgpu_flat_work_group_size(NT, NT),
                          amdgpu_waves_per_eu(2, 2)))
void fps_kernel(const float* __restrict__ pts_t,        // (B,3,N)
                float* __restrict__ out,                // (B,3,NPOINT)
                unsigned long long* __restrict__ gslot) // [B][NPOINT][NSLOT]
{
#pragma clang fp contract(off)
    const int blk = blockIdx.x;
    const int b = blk & (BATCH - 1);          // batch -> XCD (round-robin)
    const int k = blk >> 3;                   // sub-block within batch
    const int t = threadIdx.x;
    const int w = t >> 6;                     // wave id
    const int l = t & 63;                     // lane id

    const float* __restrict__ px = pts_t + (size_t)b * 3 * N;
    const float* __restrict__ py = px + N;
    const float* __restrict__ pz = py + N;
    const f2* __restrict__ px2 = (const f2*)px;
    const f2* __restrict__ py2 = (const f2*)py;
    const f2* __restrict__ pz2 = (const f2*)pz;
    float* outx = out + (size_t)b * 3 * NPOINT;
    float* outy = outx + NPOINT;
    float* outz = outy + NPOINT;

    unsigned long long* __restrict__ slotb = gslot + (size_t)b * NPOINT * NSLOT;
    const int myslot = k * NW + w;

    // ---- all point state in registers: 8 f2 per array (16 pts/thread) ----
#define DECL(g) f2 x##g, y##g, z##g, T##g;
    REP8(DECL)
#undef DECL

#define LOADG(g) { const int q = k * QB + (g) * NT + t;           \
                   x##g = px2[q]; y##g = py2[q]; z##g = pz2[q];   \
                   T##g = (f2){1e10f, 1e10f}; }
    REP8(LOADG)
#undef LOADG

    // First selected index is 0 (reference: idx[0] = 0).
    float lx = px[0], ly = py[0], lz = pz[0];
    if (k == 0 && t == 0) { outx[0] = lx; outy[0] = ly; outz[0] = lz; }

    for (int j = 1; j < NPOINT; ++j) {
        const f2 lx2 = (f2){lx, lx};
        const f2 ly2 = (f2){ly, ly};
        const f2 lz2 = (f2){lz, lz};

        // --- update temps vs pivot; per-lane running max (pure VALU) ---
        f2 mx = (f2){0.0f, 0.0f};
#define UPD(g) { f2 dz = z##g - lz2;                                     \
                 f2 dx = x##g - lx2;                                     \
                 f2 dy = y##g - ly2;                                     \
                 f2 s  = (dx * dx + dy * dy) + dz * dz; /* numpy order */\
                 T##g.x = fminf(T##g.x, s.x);                            \
                 T##g.y = fminf(T##g.y, s.y);                            \
                 mx.x = fmaxf(mx.x, T##g.x);                             \
                 mx.y = fmaxf(mx.y, T##g.y); }
        REP8(UPD)
#undef UPD
        const float vlane = fmaxf(mx.x, mx.y);   // lane-local max

        // --- lane-local argmax (lowest original idx achieving vlane) ---
        int cand = N;
#define SCANG(g) { const int q = k * QB + (g) * NT + t;           \
                   cand = (T##g.y == vlane) ? 2 * q + 1 : cand;   \
                   cand = (T##g.x == vlane) ? 2 * q     : cand; }
        REP8R(SCANG)                       // descending -> lowest idx wins
#undef SCANG

        // --- per-lane key, wave max-reduce (lexicographic: dist, -idx) ---
        unsigned long long key =
            ((unsigned long long)__float_as_uint(vlane) << 32) |
            (unsigned)(N - cand);
#pragma unroll
        for (int off = 32; off >= 1; off >>= 1) {
            const unsigned long long o = __shfl_xor(key, off);
            key = o > key ? o : key;
        }

        // --- publish this wave's key (self-contained flag, always != 0) ---
        unsigned long long* __restrict__ slots = slotb + (size_t)j * NSLOT;
        if (l == 0)
            __hip_atomic_store(&slots[myslot], key, __ATOMIC_RELAXED,
                               __HIP_MEMORY_SCOPE_AGENT);

        // --- poll all 32 slots, one per lane (loads, not RMWs) ---
        unsigned long long o = 0ull;
        if (l < NSLOT) {
            do {
                o = __hip_atomic_load(&slots[l], __ATOMIC_RELAXED,
                                      __HIP_MEMORY_SCOPE_AGENT);
            } while (o == 0ull);
        }
#pragma unroll
        for (int off = 16; off >= 1; off >>= 1) {
            const unsigned long long s = __shfl_xor(o, off);
            o = s > o ? s : o;
        }
        const unsigned long long K = __shfl(o, 0);   // broadcast to 64 lanes

        const int sel =
            __builtin_amdgcn_readfirstlane(N - (int)(unsigned)(K & 0xffffffffu));
        lx = px[sel];                      // uniform -> scalar load (L2-hit)
        ly = py[sel];
        lz = pz[sel];
        if (k == 0 && t == 0) { outx[j] = lx; outy[j] = ly; outz[j] = lz; }
    }
}

extern "C" void kernel_launch(void* const* d_in, const int* in_sizes, int n_in,
                              void* d_out, int out_size, void* d_ws, size_t ws_size,
                              hipStream_t stream) {
    // d_in[0]: points_xyz (B,N,3) — unused
    // d_in[1]: points_xyz_t (B,3,N)
    // d_in[2]: features_with_xyz (B,67,N) — unused
    // d_ws: gslot u64[B][NPOINT][NSLOT] = 4 MiB, zeroed per launch
    const float* pts_t = (const float*)d_in[1];
    float* out = (float*)d_out;
    unsigned long long* gslot = (unsigned long long*)d_ws;
    hipMemsetAsync(d_ws, 0,
                   (size_t)BATCH * NPOINT * NSLOT * sizeof(unsigned long long),
                   stream);
    fps_kernel<<<NBLK, NT, 0, stream>>>(pts_t, out, gslot);
}

// Round 8
// 4064.334 us; speedup vs baseline: 1.9672x; 1.9672x over previous
//
#include <hip/hip_runtime.h>

#define BATCH 8
#define KSPLIT 4                       // blocks (CUs) per batch
#define NBLK (BATCH * KSPLIT)          // 32 blocks, all co-resident
#define N 32768
#define NPOINT 2048
#define NT 512                         // threads per block (8 waves)
#define NW 8                           // waves per block
#define QB (N / 2 / KSPLIT)            // f2 elems per block = 4096

typedef __attribute__((ext_vector_type(2))) float f2;

// Multi-CU FPS, round-7 protocol: r4's block-level topology + r6's
// data-rides-the-flag sync.  Each batch split over KSPLIT blocks swizzled
// onto one XCD (blk = k*8 + b).  All point state in registers (16 pts/thr).
// Per iteration:
//   1. UPD + per-lane u64 key (dist_bits<<32 | N-idx) + 6-step wave reduce
//   2. wave leaders: LDS atomicMax into s_key[j]  (per-iter slot, no reset)
//   3. one __syncthreads
//   4. t0: ONE relaxed agent-scope STORE of the block key to gslot[b][j][k]
//      (self-contained flag, always nonzero; no RMW, no fence, no counter)
//   5. every wave: lanes 0..3 poll the 4 block slots (plain atomic loads),
//      2-step shfl max reduce, lane-0 broadcast -> sel; no second barrier
// Max dist + lowest original index on ties (dist >= 0 -> bits monotone).
// Bit-exact numpy semantics: contract off, (xx+yy)+zz order, no FMA.

#define REP8(M)  M(0) M(1) M(2) M(3) M(4) M(5) M(6) M(7)
#define REP8R(M) M(7) M(6) M(5) M(4) M(3) M(2) M(1) M(0)

__global__ __attribute__((amdgpu_flat_work_group_size(NT, NT),
                          amdgpu_waves_per_eu(2, 2)))
void fps_kernel(const float* __restrict__ pts_t,        // (B,3,N)
                float* __restrict__ out,                // (B,3,NPOINT)
                unsigned long long* __restrict__ gslot) // [B][NPOINT][KSPLIT]
{
#pragma clang fp contract(off)
    __shared__ unsigned long long s_key[NPOINT];   // 16 KiB, one slot/iter

    const int blk = blockIdx.x;
    const int b = blk & (BATCH - 1);          // batch -> XCD (round-robin)
    const int k = blk >> 3;                   // sub-block within batch
    const int t = threadIdx.x;
    const int l = t & 63;                     // lane id

    const float* __restrict__ px = pts_t + (size_t)b * 3 * N;
    const float* __restrict__ py = px + N;
    const float* __restrict__ pz = py + N;
    const f2* __restrict__ px2 = (const f2*)px;
    const f2* __restrict__ py2 = (const f2*)py;
    const f2* __restrict__ pz2 = (const f2*)pz;
    float* outx = out + (size_t)b * 3 * NPOINT;
    float* outy = outx + NPOINT;
    float* outz = outy + NPOINT;

    unsigned long long* __restrict__ slotb =
        gslot + (size_t)b * NPOINT * KSPLIT;

    // ---- all point state in registers: 8 f2 per array (16 pts/thread) ----
#define DECL(g) f2 x##g, y##g, z##g, T##g;
    REP8(DECL)
#undef DECL

#define LOADG(g) { const int q = k * QB + (g) * NT + t;           \
                   x##g = px2[q]; y##g = py2[q]; z##g = pz2[q];   \
                   T##g = (f2){1e10f, 1e10f}; }
    REP8(LOADG)
#undef LOADG

    // zero per-iteration LDS key slots (once)
    for (int i = t; i < NPOINT; i += NT) s_key[i] = 0ull;

    // First selected index is 0 (reference: idx[0] = 0).
    float lx = px[0], ly = py[0], lz = pz[0];
    if (k == 0 && t == 0) { outx[0] = lx; outy[0] = ly; outz[0] = lz; }
    __syncthreads();

    for (int j = 1; j < NPOINT; ++j) {
        const f2 lx2 = (f2){lx, lx};
        const f2 ly2 = (f2){ly, ly};
        const f2 lz2 = (f2){lz, lz};

        // --- update temps vs pivot; per-lane running max (pure VALU) ---
        f2 mx = (f2){0.0f, 0.0f};
#define UPD(g) { f2 dz = z##g - lz2;                                     \
                 f2 dx = x##g - lx2;                                     \
                 f2 dy = y##g - ly2;                                     \
                 f2 s  = (dx * dx + dy * dy) + dz * dz; /* numpy order */\
                 T##g.x = fminf(T##g.x, s.x);                            \
                 T##g.y = fminf(T##g.y, s.y);                            \
                 mx.x = fmaxf(mx.x, T##g.x);                             \
                 mx.y = fmaxf(mx.y, T##g.y); }
        REP8(UPD)
#undef UPD
        const float vlane = fmaxf(mx.x, mx.y);   // lane-local max

        // --- lane-local argmax (lowest original idx achieving vlane) ---
        int cand = N;
#define SCANG(g) { const int q = k * QB + (g) * NT + t;           \
                   cand = (T##g.y == vlane) ? 2 * q + 1 : cand;   \
                   cand = (T##g.x == vlane) ? 2 * q     : cand; }
        REP8R(SCANG)                       // descending -> lowest idx wins
#undef SCANG

        // --- per-lane key, wave max-reduce (lexicographic: dist, -idx) ---
        unsigned long long key =
            ((unsigned long long)__float_as_uint(vlane) << 32) |
            (unsigned)(N - cand);
#pragma unroll
        for (int off = 32; off >= 1; off >>= 1) {
            const unsigned long long o = __shfl_xor(key, off);
            key = o > key ? o : key;
        }

        // --- intra-block combine: one LDS atomic per wave, one barrier ---
        if (l == 0) atomicMax(&s_key[j], key);
        __syncthreads();

        // --- publish block key: ONE fire-and-forget store (t0 only) ---
        unsigned long long* __restrict__ slots = slotb + (size_t)j * KSPLIT;
        if (t == 0)
            __hip_atomic_store(&slots[k], s_key[j], __ATOMIC_RELAXED,
                               __HIP_MEMORY_SCOPE_AGENT);

        // --- every wave polls the 4 block slots (lanes 0..3) ---
        unsigned long long o = 0ull;
        if (l < KSPLIT) {
            do {
                o = __hip_atomic_load(&slots[l], __ATOMIC_RELAXED,
                                      __HIP_MEMORY_SCOPE_AGENT);
            } while (o == 0ull);
        }
#pragma unroll
        for (int off = 2; off >= 1; off >>= 1) {   // reduce lanes 0..3
            const unsigned long long s = __shfl_xor(o, off);
            o = s > o ? s : o;
        }
        const unsigned long long K = __shfl(o, 0); // broadcast to 64 lanes

        const int sel =
            __builtin_amdgcn_readfirstlane(N - (int)(unsigned)(K & 0xffffffffu));
        lx = px[sel];                      // uniform -> scalar load (L2-hit)
        ly = py[sel];
        lz = pz[sel];
        if (k == 0 && t == 0) { outx[j] = lx; outy[j] = ly; outz[j] = lz; }
    }
}

extern "C" void kernel_launch(void* const* d_in, const int* in_sizes, int n_in,
                              void* d_out, int out_size, void* d_ws, size_t ws_size,
                              hipStream_t stream) {
    // d_in[0]: points_xyz (B,N,3) — unused
    // d_in[1]: points_xyz_t (B,3,N)
    // d_in[2]: features_with_xyz (B,67,N) — unused
    // d_ws: gslot u64[B][NPOINT][KSPLIT] = 512 KiB, zeroed per launch
    const float* pts_t = (const float*)d_in[1];
    float* out = (float*)d_out;
    unsigned long long* gslot = (unsigned long long*)d_ws;
    hipMemsetAsync(d_ws, 0,
                   (size_t)BATCH * NPOINT * KSPLIT * sizeof(unsigned long long),
                   stream);
    fps_kernel<<<NBLK, NT, 0, stream>>>(pts_t, out, gslot);
}